// Round 4
// baseline (326.976 us; speedup 1.0000x reference)
//
#include <hip/hip_runtime.h>
#include <math.h>

// ---------------------------------------------------------------------------
// SplineCNN net, MI355X. All geometry compile-time (tiled meshgrid).
// R9: (a) prepM deleted -- GEMM B-tiles computed inline from W2/W3/root
// (L2-resident, 4 cached loads + 4 FMA per staged element, bit-identical
// arithmetic). (b) split-K reductions fused into the GEMMs via deterministic
// last-block election (threadfence + atomicAdd counter, fixed sum order).
// 4 dispatches:
//   D1 s1p1 (interior fast path) + counter-zero block
//   D2 gemm2_red: 36c x 4rt x S=3 = 432 blk; last block per (pooled r, rt)
//      does sum3+bias+ELU+pool 6x6->4x4 -> h2p
//   D3 gemm3_red: 16c x 4rt x S=9 = 576 blk; invalid-dir blocks zero-store;
//      last block per (2x2 r, rt) does sum9+bias+ELU+pool 4x4->2x2 -> Al
//   D4 fc: reads Al (256KB, was 9.4MB of P), FC1 split-K, FC2, log_softmax
// ---------------------------------------------------------------------------

#define DEV __device__ __forceinline__

DEV float elu_f(float v) { return v > 0.f ? v : expm1f(v); }

DEV void corners(float p0, float p1,
                 int& k00, int& k01, int& k10, int& k11,
                 float& w00, float& w01, float& w10, float& w11) {
  float v0 = fminf(fmaxf(p0, 0.f), 1.f) * 4.f;
  float v1 = fminf(fmaxf(p1, 0.f), 1.f) * 4.f;
  int i0 = (int)v0; i0 = i0 > 4 ? 4 : i0;
  int j0 = (int)v1; j0 = j0 > 4 ? 4 : j0;
  float f0 = v0 - (float)i0;
  float f1 = v1 - (float)j0;
  int i1 = i0 + 1 > 4 ? 4 : i0 + 1;
  int j1 = j0 + 1 > 4 ? 4 : j0 + 1;
  k00 = i0 * 5 + j0; k01 = i0 * 5 + j1; k10 = i1 * 5 + j0; k11 = i1 * 5 + j1;
  w00 = (1.f - f0) * (1.f - f1); w01 = (1.f - f0) * f1;
  w10 = f0 * (1.f - f1);         w11 = f0 * f1;
}

DEV float cellpos(int c, int gw) {
  return (gw == 6) ? (c < 5 ? 2.f + 5.f * (float)c : 26.f)
                   : (c < 3 ? 2.f + 7.5f * (float)c : 24.f);
}

// 6x6 -> 4x4 pool class map {0,1,1,2,3,3}
DEV int ymap6(int c) { return c == 0 ? 0 : (c <= 2 ? 1 : (c == 3 ? 2 : 3)); }

__constant__ int c_dys[8] = {-1, -1, -1, 0, 0, 1, 1, 1};
__constant__ int c_dxs[8] = {-1, 0, 1, -1, 1, -1, 0, 1};

// ---------------- D1: L1 stencil + ELU + pool 28x28->6x6 (+cnt zero) -------
DEV void s1p1_body(int id, const float* __restrict__ xin,
                   const float* __restrict__ W1, const float* __restrict__ root1,
                   const float* __restrict__ b1, float* __restrict__ h1p) {
  int g = id & 31, cell = id >> 5;
  int b = cell / 36, r = cell % 36;
  int cy = r / 6, cx = r % 6;
  int y0 = cy * 5, y1 = y0 + 5 > 28 ? 28 : y0 + 5;
  int x0 = cx * 5, x1 = x0 + 5 > 28 ? 28 : x0 + 5;
  float Wreg[8];
#pragma unroll
  for (int d = 0; d < 8; d++) {
    int k = (2 * c_dxs[d] + 2) * 5 + (2 * c_dys[d] + 2);  // frac==0
    Wreg[d] = W1[k * 32 + g];
  }
  float rt = root1[g], bs = b1[g];
  const float* xb = xin + b * 784;
  float vmax = -3.4e38f;
  for (int y = y0; y < y1; y++) {
    bool yin = (y > 0) && (y < 27);
    for (int x = x0; x < x1; x++) {
      float v;
      if (yin && (x > 0) && (x < 27)) {
        float acc = 0.f;
#pragma unroll
        for (int d = 0; d < 8; d++)
          acc += xb[(y - c_dys[d]) * 28 + (x - c_dxs[d])] * Wreg[d];
        v = acc * 0.125f + xb[y * 28 + x] * rt + bs;
      } else {
        float acc = 0.f;
#pragma unroll
        for (int d = 0; d < 8; d++) {
          int sy = y - c_dys[d], sx = x - c_dxs[d];
          if (sy >= 0 && sy < 28 && sx >= 0 && sx < 28)
            acc += xb[sy * 28 + sx] * Wreg[d];
        }
        float cnt = (float)((1 + (y > 0) + (y < 27)) * (1 + (x > 0) + (x < 27)) - 1);
        v = acc * (1.f / cnt) + xb[y * 28 + x] * rt + bs;
      }
      vmax = fmaxf(vmax, elu_f(v));
    }
  }
  h1p[cell * 32 + g] = vmax;
}

__global__ __launch_bounds__(256) void s1p1z_kernel(
    const float* __restrict__ x, const float* __restrict__ W1,
    const float* __restrict__ root1, const float* __restrict__ b1,
    float* __restrict__ h1p, unsigned int* __restrict__ cnt) {
  int vb = blockIdx.x;
  if (vb < 1152) s1p1_body(vb * 256 + threadIdx.x, x, W1, root1, b1, h1p);
  else if (threadIdx.x < 80) cnt[threadIdx.x] = 0u;  // 64 L2-groups + 16 L3
}

// ---------------- D2: L2 class-GEMM (inline B) + fused reduction -----------
// grid dim3(4 rowtiles, 36 cells, 3 splits). Partials P[s][c][256][64].
// Last block per group (pooled r, rt) reduces sum3+bias+ELU+pool -> h2p.
__global__ __launch_bounds__(256) void gemm2_red_kernel(
    const float* __restrict__ X, const float* __restrict__ W2,
    const float* __restrict__ root2, const float* __restrict__ b2,
    float* __restrict__ P, float* __restrict__ h2p,
    unsigned int* __restrict__ cnt) {
  __shared__ float At[16][64];
  __shared__ float Bt[16][64];
  __shared__ int nbL[9];
  __shared__ unsigned int leadv;
  int t = threadIdx.x;
  int rt = blockIdx.x, c = blockIdx.y, s = blockIdx.z;
  int b0 = rt * 64;
  int cy = c / 6, cx = c % 6;
  if (t < 9) {
    int nbv = c;
    if (t < 8) {
      int sy = cy - c_dys[t], sx = cx - c_dxs[t];
      nbv = (sy >= 0 && sy < 6 && sx >= 0 && sx < 6) ? sy * 6 + sx : c;
    }
    nbL[t] = nbv;
  }
  __syncthreads();

  int tx = t & 15, ty = t >> 4;
  int kqA = (t & 3) * 4, rA = t >> 2;
  int bkB = t >> 4, bnB = (t & 15) * 4;
  float acc[4][4];
#pragma unroll
  for (int i = 0; i < 4; i++)
#pragma unroll
    for (int j = 0; j < 4; j++) acc[i][j] = 0.f;

  for (int k0 = 0; k0 < 96; k0 += 16) {
    int kA = k0 + kqA;
    int dA = s * 3 + (kA >> 5);
    int fA = kA & 31;
    float4 xv = *(const float4*)&X[(((b0 + rA) * 36 + nbL[dA]) << 5) + fA];
    int kB = k0 + bkB;
    int dB = s * 3 + (kB >> 5);  // uniform within chunk
    int fB = kB & 31;
    float4 bv;
    if (dB == 8) {
      bv = *(const float4*)&root2[fB * 64 + bnB];
    } else {
      int sy = cy - c_dys[dB], sx = cx - c_dxs[dB];
      if (sy >= 0 && sy < 6 && sx >= 0 && sx < 6) {
        int cn = (1 + (cy > 0) + (cy < 5)) * (1 + (cx > 0) + (cx < 5)) - 1;
        float invc = 1.f / (float)cn;
        float p0 = (cellpos(cx, 6) - cellpos(sx, 6)) * 0.1f + 0.5f;
        float p1 = (cellpos(cy, 6) - cellpos(sy, 6)) * 0.1f + 0.5f;
        int k00, k01, k10, k11; float w00, w01, w10, w11;
        corners(p0, p1, k00, k01, k10, k11, w00, w01, w10, w11);
        float4 a0 = *(const float4*)&W2[(k00 * 32 + fB) * 64 + bnB];
        float4 a1 = *(const float4*)&W2[(k01 * 32 + fB) * 64 + bnB];
        float4 a2 = *(const float4*)&W2[(k10 * 32 + fB) * 64 + bnB];
        float4 a3 = *(const float4*)&W2[(k11 * 32 + fB) * 64 + bnB];
        bv.x = invc * (w00 * a0.x + w01 * a1.x + w10 * a2.x + w11 * a3.x);
        bv.y = invc * (w00 * a0.y + w01 * a1.y + w10 * a2.y + w11 * a3.y);
        bv.z = invc * (w00 * a0.z + w01 * a1.z + w10 * a2.z + w11 * a3.z);
        bv.w = invc * (w00 * a0.w + w01 * a1.w + w10 * a2.w + w11 * a3.w);
      } else {
        bv.x = bv.y = bv.z = bv.w = 0.f;
      }
    }
    __syncthreads();
    At[kqA + 0][rA] = xv.x; At[kqA + 1][rA] = xv.y;
    At[kqA + 2][rA] = xv.z; At[kqA + 3][rA] = xv.w;
    *(float4*)&Bt[bkB][bnB] = bv;
    __syncthreads();
#pragma unroll
    for (int kk = 0; kk < 16; kk++) {
      float4 a = *(const float4*)&At[kk][ty * 4];
      float4 bb = *(const float4*)&Bt[kk][tx * 4];
      acc[0][0] += a.x * bb.x; acc[0][1] += a.x * bb.y; acc[0][2] += a.x * bb.z; acc[0][3] += a.x * bb.w;
      acc[1][0] += a.y * bb.x; acc[1][1] += a.y * bb.y; acc[1][2] += a.y * bb.z; acc[1][3] += a.y * bb.w;
      acc[2][0] += a.z * bb.x; acc[2][1] += a.z * bb.y; acc[2][2] += a.z * bb.z; acc[2][3] += a.z * bb.w;
      acc[3][0] += a.w * bb.x; acc[3][1] += a.w * bb.y; acc[3][2] += a.w * bb.z; acc[3][3] += a.w * bb.w;
    }
  }
  float* Pq = P + ((size_t)(s * 36 + c) * 256 + b0) * 64;
#pragma unroll
  for (int i = 0; i < 4; i++) {
    float4 v = {acc[i][0], acc[i][1], acc[i][2], acc[i][3]};
    *(float4*)&Pq[(size_t)(ty * 4 + i) * 64 + tx * 4] = v;
  }

  // ---- deterministic last-block reduction ----
  int oy = ymap6(cy), ox = ymap6(cx);
  int r = oy * 4 + ox;
  int grp = r * 4 + rt;
  int ny = (oy == 1 || oy == 3) ? 2 : 1;
  int nx = (ox == 1 || ox == 3) ? 2 : 1;
  unsigned int tgt = 3u * (unsigned int)(ny * nx);
  __threadfence();   // release partials (agent scope)
  __syncthreads();
  if (t == 0) leadv = atomicAdd(&cnt[grp], 1u);
  __syncthreads();
  if (leadv != tgt - 1u) return;
  __threadfence();   // acquire

  int ys = oy == 0 ? 0 : (oy == 1 ? 1 : (oy == 2 ? 3 : 4));
  int xs = ox == 0 ? 0 : (ox == 1 ? 1 : (ox == 2 ? 3 : 4));
  const size_t CS = (size_t)36 * 256 * 64;
#pragma unroll
  for (int i = 0; i < 4; i++) {
    int q = t + i * 256;           // 0..1023
    int row = q >> 4, gq = (q & 15) * 4;
    float4 bg = *(const float4*)&b2[gq];
    float4 vm; vm.x = vm.y = vm.z = vm.w = -3.4e38f;
    for (int yy = ys; yy < ys + ny; yy++)
      for (int xx = xs; xx < xs + nx; xx++) {
        size_t e = ((size_t)((yy * 6 + xx) * 256 + b0 + row)) * 64 + gq;
        float4 p0 = *(const float4*)&P[e];
        float4 p1 = *(const float4*)&P[CS + e];
        float4 p2 = *(const float4*)&P[2 * CS + e];
        vm.x = fmaxf(vm.x, elu_f(p0.x + p1.x + p2.x + bg.x));
        vm.y = fmaxf(vm.y, elu_f(p0.y + p1.y + p2.y + bg.y));
        vm.z = fmaxf(vm.z, elu_f(p0.z + p1.z + p2.z + bg.z));
        vm.w = fmaxf(vm.w, elu_f(p0.w + p1.w + p2.w + bg.w));
      }
    *(float4*)&h2p[((size_t)(b0 + row) * 16 + r) * 64 + gq] = vm;
  }
}

// ---------------- D3: L3 class-GEMM (inline B) + fused reduction -----------
// grid dim3(4 rowtiles, 16 cells, 9 splits=dirs). Partials P[s][c][256][64].
// Invalid-dir blocks: zero-store fast path. Last block per (2x2 r, rt)
// reduces sum9+b3+ELU+pool 4x4->2x2 -> Al[b*4+r][64].
__global__ __launch_bounds__(256) void gemm3_red_kernel(
    const float* __restrict__ X, const float* __restrict__ W3,
    const float* __restrict__ root3, const float* __restrict__ b3,
    float* __restrict__ P, float* __restrict__ Al,
    unsigned int* __restrict__ cnt) {
  __shared__ float At[16][64];
  __shared__ float Bt[16][64];
  __shared__ int nbS;
  __shared__ unsigned int leadv;
  int t = threadIdx.x;
  int rt = blockIdx.x, c = blockIdx.y, s = blockIdx.z;
  int b0 = rt * 64;
  int cy = c >> 2, cx = c & 3;

  bool valid = true;
  int sy = 0, sx = 0;
  if (s < 8) {
    sy = cy - c_dys[s]; sx = cx - c_dxs[s];
    valid = (sy >= 0 && sy < 4 && sx >= 0 && sx < 4);
  }
  if (t == 0) nbS = valid && s < 8 ? sy * 4 + sx : c;
  __syncthreads();

  int tx = t & 15, ty = t >> 4;
  float* Pq = P + ((size_t)(s * 16 + c) * 256 + b0) * 64;

  if (!valid) {
    // zero partials (44/128 (c,dir) pairs are out-of-grid)
    float4 z; z.x = z.y = z.z = z.w = 0.f;
#pragma unroll
    for (int i = 0; i < 4; i++)
      *(float4*)&Pq[(size_t)(ty * 4 + i) * 64 + tx * 4] = z;
  } else {
    int kqA = (t & 3) * 4, rA = t >> 2;
    int bkB = t >> 4, bnB = (t & 15) * 4;
    float acc[4][4];
#pragma unroll
    for (int i = 0; i < 4; i++)
#pragma unroll
      for (int j = 0; j < 4; j++) acc[i][j] = 0.f;

    // per-block scalar B coefficients (dir == s, uniform)
    int k00 = 0, k01 = 0, k10 = 0, k11 = 0;
    float w00 = 0.f, w01 = 0.f, w10 = 0.f, w11 = 0.f, invc = 0.f;
    if (s < 8) {
      int cn = (1 + (cy > 0) + (cy < 3)) * (1 + (cx > 0) + (cx < 3)) - 1;
      invc = 1.f / (float)cn;
      float p0 = (cellpos(cx, 4) - cellpos(sx, 4)) * (1.f / 15.f) + 0.5f;
      float p1 = (cellpos(cy, 4) - cellpos(sy, 4)) * (1.f / 15.f) + 0.5f;
      corners(p0, p1, k00, k01, k10, k11, w00, w01, w10, w11);
    }
    int nb = nbS;
    for (int k0 = 0; k0 < 64; k0 += 16) {
      int fA = k0 + kqA;
      float4 xv = *(const float4*)&X[(((b0 + rA) * 16 + nb) << 6) + fA];
      int fB = k0 + bkB;
      float4 bv;
      if (s == 8) {
        bv = *(const float4*)&root3[fB * 64 + bnB];
      } else {
        float4 a0 = *(const float4*)&W3[(k00 * 64 + fB) * 64 + bnB];
        float4 a1 = *(const float4*)&W3[(k01 * 64 + fB) * 64 + bnB];
        float4 a2 = *(const float4*)&W3[(k10 * 64 + fB) * 64 + bnB];
        float4 a3 = *(const float4*)&W3[(k11 * 64 + fB) * 64 + bnB];
        bv.x = invc * (w00 * a0.x + w01 * a1.x + w10 * a2.x + w11 * a3.x);
        bv.y = invc * (w00 * a0.y + w01 * a1.y + w10 * a2.y + w11 * a3.y);
        bv.z = invc * (w00 * a0.z + w01 * a1.z + w10 * a2.z + w11 * a3.z);
        bv.w = invc * (w00 * a0.w + w01 * a1.w + w10 * a2.w + w11 * a3.w);
      }
      __syncthreads();
      At[kqA + 0][rA] = xv.x; At[kqA + 1][rA] = xv.y;
      At[kqA + 2][rA] = xv.z; At[kqA + 3][rA] = xv.w;
      *(float4*)&Bt[bkB][bnB] = bv;
      __syncthreads();
#pragma unroll
      for (int kk = 0; kk < 16; kk++) {
        float4 a = *(const float4*)&At[kk][ty * 4];
        float4 bb = *(const float4*)&Bt[kk][tx * 4];
        acc[0][0] += a.x * bb.x; acc[0][1] += a.x * bb.y; acc[0][2] += a.x * bb.z; acc[0][3] += a.x * bb.w;
        acc[1][0] += a.y * bb.x; acc[1][1] += a.y * bb.y; acc[1][2] += a.y * bb.z; acc[1][3] += a.y * bb.w;
        acc[2][0] += a.z * bb.x; acc[2][1] += a.z * bb.y; acc[2][2] += a.z * bb.z; acc[2][3] += a.z * bb.w;
        acc[3][0] += a.w * bb.x; acc[3][1] += a.w * bb.y; acc[3][2] += a.w * bb.z; acc[3][3] += a.w * bb.w;
      }
    }
#pragma unroll
    for (int i = 0; i < 4; i++) {
      float4 v = {acc[i][0], acc[i][1], acc[i][2], acc[i][3]};
      *(float4*)&Pq[(size_t)(ty * 4 + i) * 64 + tx * 4] = v;
    }
  }

  // ---- deterministic last-block reduction ----
  int r2 = (cy >> 1) * 2 + (cx >> 1);
  int grp = r2 * 4 + rt;
  __threadfence();
  __syncthreads();
  if (t == 0) leadv = atomicAdd(&cnt[grp], 1u);
  __syncthreads();
  if (leadv != 35u) return;  // tgt = 9 splits * 4 cells
  __threadfence();

  int ys = (r2 >> 1) * 2, xs = (r2 & 1) * 2;
  const size_t CS = (size_t)16 * 256 * 64;
#pragma unroll
  for (int i = 0; i < 4; i++) {
    int q = t + i * 256;
    int row = q >> 4, gq = (q & 15) * 4;
    float4 bg = *(const float4*)&b3[gq];
    float4 vm; vm.x = vm.y = vm.z = vm.w = -3.4e38f;
    for (int yy = ys; yy < ys + 2; yy++)
      for (int xx = xs; xx < xs + 2; xx++) {
        size_t e = ((size_t)((yy * 4 + xx) * 256 + b0 + row)) * 64 + gq;
        float4 v = bg;
        for (int ss = 0; ss < 9; ss++) {
          float4 p = *(const float4*)&P[ss * CS + e];
          v.x += p.x; v.y += p.y; v.z += p.z; v.w += p.w;
        }
        vm.x = fmaxf(vm.x, elu_f(v.x));
        vm.y = fmaxf(vm.y, elu_f(v.y));
        vm.z = fmaxf(vm.z, elu_f(v.z));
        vm.w = fmaxf(vm.w, elu_f(v.w));
      }
    *(float4*)&Al[((size_t)(b0 + row) * 4 + r2) * 64 + gq] = vm;
  }
}

// ---------------- D4: FC head ----------------------------------------------
__global__ __launch_bounds__(256) void fc_kernel(
    const float* __restrict__ Alg, const float* __restrict__ fc1w,
    const float* __restrict__ fc1b, const float* __restrict__ fc2w,
    const float* __restrict__ fc2b, float* __restrict__ out) {
  __shared__ float Al[256];
  __shared__ float part[256];
  __shared__ float h4[128];
  __shared__ float lg[10];
  int b = blockIdx.x, t = threadIdx.x;
  Al[t] = Alg[b * 256 + t];
  __syncthreads();
  {
    int o = t & 127, half = t >> 7;
    float acc = 0.f;
    const float* wcol = fc1w + o;
#pragma unroll 8
    for (int k = half * 128; k < half * 128 + 128; k++)
      acc += Al[k] * wcol[k * 128];
    part[t] = acc;
  }
  __syncthreads();
  if (t < 128)
    h4[t] = elu_f(part[t] + part[t + 128] + fc1b[t]);
  __syncthreads();
  if (t < 10) {
    float l = fc2b[t];
#pragma unroll 8
    for (int k = 0; k < 128; k++) l += h4[k] * fc2w[k * 10 + t];
    lg[t] = l;
  }
  __syncthreads();
  if (t < 10) {
    float m = lg[0];
#pragma unroll
    for (int j = 1; j < 10; j++) m = fmaxf(m, lg[j]);
    float ssum = 0.f;
#pragma unroll
    for (int j = 0; j < 10; j++) ssum += expf(lg[j] - m);
    out[b * 10 + t] = lg[t] - m - logf(ssum);
  }
}

// ---------------------------------------------------------------------------
extern "C" void kernel_launch(void* const* d_in, const int* in_sizes, int n_in,
                              void* d_out, int out_size, void* d_ws, size_t ws_size,
                              hipStream_t stream) {
  const float* x     = (const float*)d_in[0];
  const float* W1    = (const float*)d_in[3];
  const float* root1 = (const float*)d_in[4];
  const float* b1    = (const float*)d_in[5];
  const float* W2    = (const float*)d_in[6];
  const float* root2 = (const float*)d_in[7];
  const float* b2    = (const float*)d_in[8];
  const float* W3    = (const float*)d_in[9];
  const float* root3 = (const float*)d_in[10];
  const float* b3    = (const float*)d_in[11];
  const float* fc1w  = (const float*)d_in[12];
  const float* fc1b  = (const float*)d_in[13];
  const float* fc2w  = (const float*)d_in[14];
  const float* fc2b  = (const float*)d_in[15];
  float* out = (float*)d_out;

  float* ws = (float*)d_ws;
  size_t o = 0;
  float* w_h1p = ws + o; o += (size_t)9216 * 32;          // 294912
  float* w_P   = ws + o; o += (size_t)9 * 16 * 256 * 64;  // 2359296 (>= 3*36*256*64)
  float* w_h2p = ws + o; o += (size_t)4096 * 64;          // 262144
  float* w_Al  = ws + o; o += (size_t)1024 * 64;          // 65536
  unsigned int* w_cnt = (unsigned int*)(ws + o); o += 80; // 64 + 16 counters

  // D1: s1p1 (1152 blocks) + counter zero (1 block)
  s1p1z_kernel<<<1153, 256, 0, stream>>>(x, W1, root1, b1, w_h1p, w_cnt);
  // D2: L2 class-GEMM inline-B + fused sum3+bias+ELU+pool -> h2p
  gemm2_red_kernel<<<dim3(4, 36, 3), 256, 0, stream>>>(w_h1p, W2, root2, b2,
                                                       w_P, w_h2p, w_cnt);
  // D3: L3 class-GEMM inline-B + fused sum9+bias+ELU+pool -> Al
  gemm3_red_kernel<<<dim3(4, 16, 9), 256, 0, stream>>>(w_h2p, W3, root3, b3,
                                                       w_P, w_Al, w_cnt + 64);
  // D4: FC head
  fc_kernel<<<256, 256, 0, stream>>>(w_Al, fc1w, fc1b, fc2w, fc2b, out);
}

// Round 5
// 167.867 us; speedup vs baseline: 1.9478x; 1.9478x over previous
//
#include <hip/hip_runtime.h>
#include <math.h>

// ---------------------------------------------------------------------------
// SplineCNN net, MI355X. All geometry compile-time (tiled meshgrid).
// R10: base = verified R8 skeleton (162us). R9 taught: no cross-block atomic
// elections (XCD cacheline bounce ~100us), no inline-B in K-loop (VGPR 256).
// This round: (a) single-chunk GEMMs -- K=96/64 fits LDS whole (48KB), all
// staging loads issued at once, ONE barrier instead of 12/8, neighbor ids in
// scalar regs; (b) redpool2 folded into gemm3's A-staging (pure recompute,
// bit-identical op order, no atomics) -- kills a dispatch + h2p round-trip.
// 4 dispatches:
//   D1 prep    = s1p1 (interior fast path) || prepM
//   D2 gemm2   = 36c x 4rt x S=3 = 432 blk, K=96 single-chunk -> P
//   D3 gemm3f  = 16c x 4rt x S=9(dirs) = 576 blk, K=64 single-chunk,
//                A-stage computes sum3+b2+ELU+pool(6x6->4x4) on the fly -> P2
//   D4 fc_fused= redpool3(9 partials)+pool 4x4->2x2 + FC head
// ---------------------------------------------------------------------------

#define DEV __device__ __forceinline__

DEV float elu_f(float v) { return v > 0.f ? v : expm1f(v); }

DEV void corners(float p0, float p1,
                 int& k00, int& k01, int& k10, int& k11,
                 float& w00, float& w01, float& w10, float& w11) {
  float v0 = fminf(fmaxf(p0, 0.f), 1.f) * 4.f;
  float v1 = fminf(fmaxf(p1, 0.f), 1.f) * 4.f;
  int i0 = (int)v0; i0 = i0 > 4 ? 4 : i0;
  int j0 = (int)v1; j0 = j0 > 4 ? 4 : j0;
  float f0 = v0 - (float)i0;
  float f1 = v1 - (float)j0;
  int i1 = i0 + 1 > 4 ? 4 : i0 + 1;
  int j1 = j0 + 1 > 4 ? 4 : j0 + 1;
  k00 = i0 * 5 + j0; k01 = i0 * 5 + j1; k10 = i1 * 5 + j0; k11 = i1 * 5 + j1;
  w00 = (1.f - f0) * (1.f - f1); w01 = (1.f - f0) * f1;
  w10 = f0 * (1.f - f1);         w11 = f0 * f1;
}

DEV float cellpos(int c, int gw) {
  return (gw == 6) ? (c < 5 ? 2.f + 5.f * (float)c : 26.f)
                   : (c < 3 ? 2.f + 7.5f * (float)c : 24.f);
}

__constant__ int c_dys[8] = {-1, -1, -1, 0, 0, 1, 1, 1};
__constant__ int c_dxs[8] = {-1, 0, 1, -1, 1, -1, 0, 1};

// ---------------- stage bodies --------------------------------------------

// L1 stencil (1->32) + ELU + pool 28x28->6x6. id in [0, 294912)
DEV void s1p1_body(int id, const float* __restrict__ xin,
                   const float* __restrict__ W1, const float* __restrict__ root1,
                   const float* __restrict__ b1, float* __restrict__ h1p) {
  int g = id & 31, cell = id >> 5;
  int b = cell / 36, r = cell % 36;
  int cy = r / 6, cx = r % 6;
  int y0 = cy * 5, y1 = y0 + 5 > 28 ? 28 : y0 + 5;
  int x0 = cx * 5, x1 = x0 + 5 > 28 ? 28 : x0 + 5;
  float Wreg[8];
#pragma unroll
  for (int d = 0; d < 8; d++) {
    int k = (2 * c_dxs[d] + 2) * 5 + (2 * c_dys[d] + 2);  // frac==0
    Wreg[d] = W1[k * 32 + g];
  }
  float rt = root1[g], bs = b1[g];
  const float* xb = xin + b * 784;
  float vmax = -3.4e38f;
  for (int y = y0; y < y1; y++) {
    bool yin = (y > 0) && (y < 27);
    for (int x = x0; x < x1; x++) {
      float v;
      if (yin && (x > 0) && (x < 27)) {
        float acc = 0.f;
#pragma unroll
        for (int d = 0; d < 8; d++)
          acc += xb[(y - c_dys[d]) * 28 + (x - c_dxs[d])] * Wreg[d];
        v = acc * 0.125f + xb[y * 28 + x] * rt + bs;
      } else {
        float acc = 0.f;
#pragma unroll
        for (int d = 0; d < 8; d++) {
          int sy = y - c_dys[d], sx = x - c_dxs[d];
          if (sy >= 0 && sy < 28 && sx >= 0 && sx < 28)
            acc += xb[sy * 28 + sx] * Wreg[d];
        }
        float cnt = (float)((1 + (y > 0) + (y < 27)) * (1 + (x > 0) + (x < 27)) - 1);
        v = acc * (1.f / cnt) + xb[y * 28 + x] * rt + bs;
      }
      vmax = fmaxf(vmax, elu_f(v));
    }
  }
  h1p[cell * 32 + g] = vmax;
}

// M[c][d][f][g] = invc(c) * sum_corners w * W[k][f][g]; d==8 -> root.
DEV void prepM_body(int idx, const float* __restrict__ W2,
                    const float* __restrict__ root2, const float* __restrict__ W3,
                    const float* __restrict__ root3, float* __restrict__ M2,
                    float* __restrict__ M3) {
  const int L2N = 36 * 9 * 32 * 64;
  int gw, F, c, d, f, g;
  const float *W, *root;
  float inv2M;
  float* Mout;
  int oidx;
  if (idx < L2N) {
    c = idx / 18432; int rem = idx % 18432;
    d = rem / 2048; f = (rem >> 6) & 31; g = rem & 63;
    gw = 6; F = 32; W = W2; root = root2; inv2M = 0.1f; Mout = M2; oidx = idx;
  } else {
    int j = idx - L2N;
    c = j / 36864; int rem = j % 36864;
    d = rem / 4096; f = (rem >> 6) & 63; g = rem & 63;
    gw = 4; F = 64; W = W3; root = root3; inv2M = 1.f / 15.f; Mout = M3; oidx = j;
  }
  float val = 0.f;
  if (d == 8) {
    val = root[f * 64 + g];
  } else {
    int cy = c / gw, cx = c % gw;
    int sy = cy - c_dys[d], sx = cx - c_dxs[d];
    if (sy >= 0 && sy < gw && sx >= 0 && sx < gw) {
      int cnt = (1 + (cy > 0) + (cy < gw - 1)) * (1 + (cx > 0) + (cx < gw - 1)) - 1;
      float invc = 1.f / (float)cnt;
      float p0 = (cellpos(cx, gw) - cellpos(sx, gw)) * inv2M + 0.5f;
      float p1 = (cellpos(cy, gw) - cellpos(sy, gw)) * inv2M + 0.5f;
      int k00, k01, k10, k11; float w00, w01, w10, w11;
      corners(p0, p1, k00, k01, k10, k11, w00, w01, w10, w11);
      val = invc * (w00 * W[(k00 * F + f) * 64 + g] + w01 * W[(k01 * F + f) * 64 + g] +
                    w10 * W[(k10 * F + f) * 64 + g] + w11 * W[(k11 * F + f) * 64 + g]);
    }
  }
  Mout[oidx] = val;
}

// ---------------- D1: s1p1 || prepM ----------------------------------------
__global__ __launch_bounds__(256) void prep_kernel(
    const float* __restrict__ x, const float* __restrict__ W1,
    const float* __restrict__ root1, const float* __restrict__ b1,
    const float* __restrict__ W2, const float* __restrict__ root2,
    const float* __restrict__ W3, const float* __restrict__ root3,
    float* __restrict__ h1p, float* __restrict__ M2, float* __restrict__ M3) {
  int vb = blockIdx.x, t = threadIdx.x;
  if (vb < 1152) s1p1_body(vb * 256 + t, x, W1, root1, b1, h1p);
  else           prepM_body((vb - 1152) * 256 + t, W2, root2, W3, root3, M2, M3);
}

// ---------------- D2: L2 class-GEMM, single K-chunk (K=96) -----------------
// grid dim3(4 rowtiles, 36 cells, 3 splits); P[s][c][256][64] partials.
__global__ __launch_bounds__(256) void gemm2_kernel(
    const float* __restrict__ X, const float* __restrict__ M2,
    float* __restrict__ P) {
  __shared__ float At[96][64];
  __shared__ float Bt[96][64];
  int t = threadIdx.x;
  int rt = blockIdx.x, c = blockIdx.y, s = blockIdx.z;
  int b0 = rt * 64;
  int cy = c / 6, cx = c % 6;
  // neighbor cell per dir of this split (scalar: c,s are blockIdx)
  int nb[3];
#pragma unroll
  for (int j = 0; j < 3; j++) {
    int d = s * 3 + j;
    int v = c;
    if (d < 8) {
      int sy = cy - c_dys[d], sx = cx - c_dxs[d];
      v = (sy >= 0 && sy < 6 && sx >= 0 && sx < 6) ? sy * 6 + sx : c;  // M==0
    }
    nb[j] = v;
  }

  int rA = t >> 2, kq = (t & 3) * 4;      // A: row rA, 4 ks at kq per 16-chunk
  int bkB = t >> 4, bnB = (t & 15) * 4;   // B: row bkB per 16-chunk, 4 cols
  float4 av[6], bv[6];
#pragma unroll
  for (int i = 0; i < 6; i++) {
    int fA = kq + (i & 1) * 16;           // f within the dir's 32-wide block
    av[i] = *(const float4*)&X[(((b0 + rA) * 36 + nb[i >> 1]) << 5) + fA];
    int fB = (i & 1) * 16 + bkB;
    bv[i] = *(const float4*)&M2[(size_t)(((c * 9 + s * 3 + (i >> 1)) << 5) + fB) * 64 + bnB];
  }
#pragma unroll
  for (int i = 0; i < 6; i++) {
    int kA = kq + i * 16;
    At[kA + 0][rA] = av[i].x; At[kA + 1][rA] = av[i].y;
    At[kA + 2][rA] = av[i].z; At[kA + 3][rA] = av[i].w;
    *(float4*)&Bt[i * 16 + bkB][bnB] = bv[i];
  }
  __syncthreads();

  int tx = t & 15, ty = t >> 4;
  float acc[4][4];
#pragma unroll
  for (int i = 0; i < 4; i++)
#pragma unroll
    for (int j = 0; j < 4; j++) acc[i][j] = 0.f;
#pragma unroll 4
  for (int kk = 0; kk < 96; kk++) {
    float4 a = *(const float4*)&At[kk][ty * 4];
    float4 bb = *(const float4*)&Bt[kk][tx * 4];
    acc[0][0] += a.x * bb.x; acc[0][1] += a.x * bb.y; acc[0][2] += a.x * bb.z; acc[0][3] += a.x * bb.w;
    acc[1][0] += a.y * bb.x; acc[1][1] += a.y * bb.y; acc[1][2] += a.y * bb.z; acc[1][3] += a.y * bb.w;
    acc[2][0] += a.z * bb.x; acc[2][1] += a.z * bb.y; acc[2][2] += a.z * bb.z; acc[2][3] += a.z * bb.w;
    acc[3][0] += a.w * bb.x; acc[3][1] += a.w * bb.y; acc[3][2] += a.w * bb.z; acc[3][3] += a.w * bb.w;
  }
  float* Pq = P + ((size_t)(s * 36 + c) * 256 + b0) * 64;
#pragma unroll
  for (int i = 0; i < 4; i++) {
    float4 v = {acc[i][0], acc[i][1], acc[i][2], acc[i][3]};
    *(float4*)&Pq[(size_t)(ty * 4 + i) * 64 + tx * 4] = v;
  }
}

// ---------------- D3: L3 class-GEMM, fused redpool2 A-stage (K=64) ---------
// grid dim3(4 rowtiles, 16 cells, 9 dirs); P2[s][c][256][64] partials.
// A element = h2p[b][nb][f] recomputed: max over source 6x6 cells of
// elu(P0+P1+P2+b2) -- bit-identical op order to R8's redpool2.
__global__ __launch_bounds__(256) void gemm3f_kernel(
    const float* __restrict__ P, const float* __restrict__ M3,
    const float* __restrict__ b2, float* __restrict__ P2) {
  __shared__ float At[64][64];
  __shared__ float Bt[64][64];
  int t = threadIdx.x;
  int rt = blockIdx.x, c = blockIdx.y, s = blockIdx.z;
  int b0 = rt * 64;
  int cy = c >> 2, cx = c & 3;
  int tx = t & 15, ty = t >> 4;

  int nb = c;
  if (s < 8) {
    int sy = cy - c_dys[s], sx = cx - c_dxs[s];
    if (sy < 0 || sy >= 4 || sx < 0 || sx >= 4) {
      // invalid dir: M3==0 -> partial is exactly zero; skip the GEMM
      float* Pq = P2 + ((size_t)(s * 16 + c) * 256 + b0) * 64;
      float4 z = {0.f, 0.f, 0.f, 0.f};
#pragma unroll
      for (int i = 0; i < 4; i++)
        *(float4*)&Pq[(size_t)(ty * 4 + i) * 64 + tx * 4] = z;
      return;
    }
    nb = sy * 4 + sx;
  }
  // pool region of pooled cell nb (4x4) over the 6x6 grid
  int oy = nb >> 2, ox = nb & 3;
  int ys = oy == 0 ? 0 : (oy == 1 ? 1 : (oy == 2 ? 3 : 4));
  int ny = (oy == 1 || oy == 3) ? 2 : 1;
  int xs = ox == 0 ? 0 : (ox == 1 ? 1 : (ox == 2 ? 3 : 4));
  int nx = (ox == 1 || ox == 3) ? 2 : 1;

  int rA = t >> 2, kq = (t & 3) * 4;
  int bkB = t >> 4, bnB = (t & 15) * 4;
  const size_t CS2 = (size_t)36 * 256 * 64;
#pragma unroll
  for (int i = 0; i < 4; i++) {
    int fA = kq + i * 16;
    float4 bg = *(const float4*)&b2[fA];
    float4 vm = {-3.4e38f, -3.4e38f, -3.4e38f, -3.4e38f};
    for (int yy = ys; yy < ys + ny; yy++)
      for (int xx = xs; xx < xs + nx; xx++) {
        size_t e = ((size_t)((yy * 6 + xx) * 256 + b0 + rA)) * 64 + fA;
        float4 p0 = *(const float4*)&P[e];
        float4 p1 = *(const float4*)&P[CS2 + e];
        float4 p2 = *(const float4*)&P[2 * CS2 + e];
        vm.x = fmaxf(vm.x, elu_f(p0.x + p1.x + p2.x + bg.x));
        vm.y = fmaxf(vm.y, elu_f(p0.y + p1.y + p2.y + bg.y));
        vm.z = fmaxf(vm.z, elu_f(p0.z + p1.z + p2.z + bg.z));
        vm.w = fmaxf(vm.w, elu_f(p0.w + p1.w + p2.w + bg.w));
      }
    At[fA + 0][rA] = vm.x; At[fA + 1][rA] = vm.y;
    At[fA + 2][rA] = vm.z; At[fA + 3][rA] = vm.w;
    int fB = i * 16 + bkB;
    *(float4*)&Bt[fB][bnB] =
        *(const float4*)&M3[(size_t)(((c * 9 + s) << 6) + fB) * 64 + bnB];
  }
  __syncthreads();

  float acc[4][4];
#pragma unroll
  for (int i = 0; i < 4; i++)
#pragma unroll
    for (int j = 0; j < 4; j++) acc[i][j] = 0.f;
#pragma unroll 4
  for (int kk = 0; kk < 64; kk++) {
    float4 a = *(const float4*)&At[kk][ty * 4];
    float4 bb = *(const float4*)&Bt[kk][tx * 4];
    acc[0][0] += a.x * bb.x; acc[0][1] += a.x * bb.y; acc[0][2] += a.x * bb.z; acc[0][3] += a.x * bb.w;
    acc[1][0] += a.y * bb.x; acc[1][1] += a.y * bb.y; acc[1][2] += a.y * bb.z; acc[1][3] += a.y * bb.w;
    acc[2][0] += a.z * bb.x; acc[2][1] += a.z * bb.y; acc[2][2] += a.z * bb.z; acc[2][3] += a.z * bb.w;
    acc[3][0] += a.w * bb.x; acc[3][1] += a.w * bb.y; acc[3][2] += a.w * bb.z; acc[3][3] += a.w * bb.w;
  }
  float* Pq = P2 + ((size_t)(s * 16 + c) * 256 + b0) * 64;
#pragma unroll
  for (int i = 0; i < 4; i++) {
    float4 v = {acc[i][0], acc[i][1], acc[i][2], acc[i][3]};
    *(float4*)&Pq[(size_t)(ty * 4 + i) * 64 + tx * 4] = v;
  }
}

// ---- D4: redpool3 (9 partials) + pool 4x4->2x2 + FC head, 1 block/image ---
__global__ __launch_bounds__(256) void fc_fused_kernel(
    const float* __restrict__ P2, const float* __restrict__ b3,
    const float* __restrict__ fc1w, const float* __restrict__ fc1b,
    const float* __restrict__ fc2w, const float* __restrict__ fc2b,
    float* __restrict__ out) {
  __shared__ float h3[16][64];
  __shared__ float Al[256];
  __shared__ float part[256];
  __shared__ float h4[128];
  __shared__ float lg[10];
  int b = blockIdx.x, t = threadIdx.x;
  const size_t CS = (size_t)16 * 256 * 64;
#pragma unroll
  for (int i = 0; i < 4; i++) {
    int idx = i * 256 + t;            // 0..1023
    int cell = idx >> 6, g = idx & 63;
    float v = b3[g];
    size_t e = (size_t)(cell * 256 + b) * 64 + g;
#pragma unroll
    for (int q = 0; q < 9; q++) v += P2[q * CS + e];
    h3[cell][g] = elu_f(v);
  }
  __syncthreads();
  {
    int r = t >> 6, g = t & 63;
    int oy = r >> 1, ox = r & 1;
    float m = -3.4e38f;
#pragma unroll
    for (int i = 0; i < 2; i++)
#pragma unroll
      for (int j = 0; j < 2; j++)
        m = fmaxf(m, h3[(oy * 2 + i) * 4 + (ox * 2 + j)][g]);
    Al[t] = m;
  }
  __syncthreads();
  {
    int o = t & 127, half = t >> 7;
    float acc = 0.f;
    const float* wcol = fc1w + o;
#pragma unroll 8
    for (int k = half * 128; k < half * 128 + 128; k++)
      acc += Al[k] * wcol[k * 128];
    part[t] = acc;
  }
  __syncthreads();
  if (t < 128)
    h4[t] = elu_f(part[t] + part[t + 128] + fc1b[t]);
  __syncthreads();
  if (t < 10) {
    float l = fc2b[t];
#pragma unroll 8
    for (int k = 0; k < 128; k++) l += h4[k] * fc2w[k * 10 + t];
    lg[t] = l;
  }
  __syncthreads();
  if (t < 10) {
    float m = lg[0];
#pragma unroll
    for (int j = 1; j < 10; j++) m = fmaxf(m, lg[j]);
    float ssum = 0.f;
#pragma unroll
    for (int j = 0; j < 10; j++) ssum += expf(lg[j] - m);
    out[b * 10 + t] = lg[t] - m - logf(ssum);
  }
}

// ---------------------------------------------------------------------------
extern "C" void kernel_launch(void* const* d_in, const int* in_sizes, int n_in,
                              void* d_out, int out_size, void* d_ws, size_t ws_size,
                              hipStream_t stream) {
  const float* x     = (const float*)d_in[0];
  const float* W1    = (const float*)d_in[3];
  const float* root1 = (const float*)d_in[4];
  const float* b1    = (const float*)d_in[5];
  const float* W2    = (const float*)d_in[6];
  const float* root2 = (const float*)d_in[7];
  const float* b2    = (const float*)d_in[8];
  const float* W3    = (const float*)d_in[9];
  const float* root3 = (const float*)d_in[10];
  const float* b3    = (const float*)d_in[11];
  const float* fc1w  = (const float*)d_in[12];
  const float* fc1b  = (const float*)d_in[13];
  const float* fc2w  = (const float*)d_in[14];
  const float* fc2b  = (const float*)d_in[15];
  float* out = (float*)d_out;

  float* ws = (float*)d_ws;
  size_t o = 0;
  float* w_h1p = ws + o; o += (size_t)9216 * 32;          // 294912
  float* w_M2  = ws + o; o += (size_t)36 * 9 * 32 * 64;   // 663552
  float* w_M3  = ws + o; o += (size_t)16 * 9 * 64 * 64;   // 589824
  float* w_P   = ws + o; o += (size_t)3 * 36 * 256 * 64;  // 1769472 (L2 partials)
  float* w_P2  = ws + o; o += (size_t)9 * 16 * 256 * 64;  // 2359296 (L3 partials)

  // D1: s1p1 (1152 blocks) || prepM (4896 blocks)
  prep_kernel<<<6048, 256, 0, stream>>>(x, W1, root1, b1, W2, root2, W3, root3,
                                        w_h1p, w_M2, w_M3);
  // D2: L2 class-GEMM, single K-chunk
  gemm2_kernel<<<dim3(4, 36, 3), 256, 0, stream>>>(w_h1p, w_M2, w_P);
  // D3: L3 class-GEMM with fused redpool2 A-staging
  gemm3f_kernel<<<dim3(4, 16, 9), 256, 0, stream>>>(w_P, w_M3, b2, w_P2);
  // D4: redpool3 + FC head
  fc_fused_kernel<<<256, 256, 0, stream>>>(w_P2, b3, fc1w, fc1b, fc2w, fc2b, out);
}

// Round 7
// 161.522 us; speedup vs baseline: 2.0243x; 1.0393x over previous
//
#include <hip/hip_runtime.h>
#include <math.h>

// ---------------------------------------------------------------------------
// SplineCNN net, MI355X. All geometry compile-time (tiled meshgrid).
// Base = verified R8 skeleton (162us, 5 dispatches). R10 taught: recompute-
// fusion multiplied by consumer fan-out (9x) loses to a dedicated pass.
// R11 changes ONE thing: prepM restructured from per-element blocks (every
// thread redoing ~6 int divides + corners()) to per-(cell,dir) blocks with
// coefficients computed once in scalar regs; threads stream float4
// out = invc*(w00*A + w01*B + w10*C + w11*D)  [same expr/assoc -> identical M]
// prep: 6048 -> 1620 blocks.
//   D1 prep     = s1p1 (interior fast path) || prepM2(324) || prepM3(144)
//   D2 gemm2    = 36c x 4rt x S=3 = 432 blk (R8 multi-chunk form) -> P
//   D3 redpool2 = sum3+bias+ELU+pool 6x6->4x4 -> h2p
//   D4 gemm3    = 16c x 4rt x S=9 = 576 blk -> P
//   D5 fc_fused = redpool3 + pool 4x4->2x2 + FC head
// (R11 bench was an infra failure -- resubmitting the identical experiment.)
// ---------------------------------------------------------------------------

#define DEV __device__ __forceinline__

DEV float elu_f(float v) { return v > 0.f ? v : expm1f(v); }

DEV void corners(float p0, float p1,
                 int& k00, int& k01, int& k10, int& k11,
                 float& w00, float& w01, float& w10, float& w11) {
  float v0 = fminf(fmaxf(p0, 0.f), 1.f) * 4.f;
  float v1 = fminf(fmaxf(p1, 0.f), 1.f) * 4.f;
  int i0 = (int)v0; i0 = i0 > 4 ? 4 : i0;
  int j0 = (int)v1; j0 = j0 > 4 ? 4 : j0;
  float f0 = v0 - (float)i0;
  float f1 = v1 - (float)j0;
  int i1 = i0 + 1 > 4 ? 4 : i0 + 1;
  int j1 = j0 + 1 > 4 ? 4 : j0 + 1;
  k00 = i0 * 5 + j0; k01 = i0 * 5 + j1; k10 = i1 * 5 + j0; k11 = i1 * 5 + j1;
  w00 = (1.f - f0) * (1.f - f1); w01 = (1.f - f0) * f1;
  w10 = f0 * (1.f - f1);         w11 = f0 * f1;
}

DEV float cellpos(int c, int gw) {
  return (gw == 6) ? (c < 5 ? 2.f + 5.f * (float)c : 26.f)
                   : (c < 3 ? 2.f + 7.5f * (float)c : 24.f);
}

__constant__ int c_dys[8] = {-1, -1, -1, 0, 0, 1, 1, 1};
__constant__ int c_dxs[8] = {-1, 0, 1, -1, 1, -1, 0, 1};

// ---------------- stage bodies --------------------------------------------

// L1 stencil (1->32) + ELU + pool 28x28->6x6. id in [0, 294912)
DEV void s1p1_body(int id, const float* __restrict__ xin,
                   const float* __restrict__ W1, const float* __restrict__ root1,
                   const float* __restrict__ b1, float* __restrict__ h1p) {
  int g = id & 31, cell = id >> 5;
  int b = cell / 36, r = cell % 36;
  int cy = r / 6, cx = r % 6;
  int y0 = cy * 5, y1 = y0 + 5 > 28 ? 28 : y0 + 5;
  int x0 = cx * 5, x1 = x0 + 5 > 28 ? 28 : x0 + 5;
  float Wreg[8];
#pragma unroll
  for (int d = 0; d < 8; d++) {
    int k = (2 * c_dxs[d] + 2) * 5 + (2 * c_dys[d] + 2);  // frac==0
    Wreg[d] = W1[k * 32 + g];
  }
  float rt = root1[g], bs = b1[g];
  const float* xb = xin + b * 784;
  float vmax = -3.4e38f;
  for (int y = y0; y < y1; y++) {
    bool yin = (y > 0) && (y < 27);
    for (int x = x0; x < x1; x++) {
      float v;
      if (yin && (x > 0) && (x < 27)) {
        float acc = 0.f;
#pragma unroll
        for (int d = 0; d < 8; d++)
          acc += xb[(y - c_dys[d]) * 28 + (x - c_dxs[d])] * Wreg[d];
        v = acc * 0.125f + xb[y * 28 + x] * rt + bs;
      } else {
        float acc = 0.f;
#pragma unroll
        for (int d = 0; d < 8; d++) {
          int sy = y - c_dys[d], sx = x - c_dxs[d];
          if (sy >= 0 && sy < 28 && sx >= 0 && sx < 28)
            acc += xb[sy * 28 + sx] * Wreg[d];
        }
        float cnt = (float)((1 + (y > 0) + (y < 27)) * (1 + (x > 0) + (x < 27)) - 1);
        v = acc * (1.f / cnt) + xb[y * 28 + x] * rt + bs;
      }
      vmax = fmaxf(vmax, elu_f(v));
    }
  }
  h1p[cell * 32 + g] = vmax;
}

// prepM, per-(c,d) block: coefficients uniform -> computed once, threads
// stream float4. QUADS = (F*64)/4 / 256 per thread.
template <int F, int GWD>  // F=32 gw=6 (M2) | F=64 gw=4 (M3)
DEV void prepM_blk(int bid, int t, const float* __restrict__ W,
                   const float* __restrict__ root, float* __restrict__ Mout) {
  int c = bid / 9, d = bid - c * 9;
  float* dst = Mout + (size_t)(c * 9 + d) * F * 64;
  constexpr int QUADS = (F * 64 / 4) / 256;  // 2 for M2, 4 for M3
  if (d == 8) {
#pragma unroll
    for (int i = 0; i < QUADS; i++) {
      int q = t + i * 256;
      *(float4*)&dst[q * 4] = *(const float4*)&root[q * 4];
    }
    return;
  }
  int cy = c / GWD, cx = c - cy * GWD;
  int sy = cy - c_dys[d], sx = cx - c_dxs[d];
  if (sy < 0 || sy >= GWD || sx < 0 || sx >= GWD) {
    float4 z = {0.f, 0.f, 0.f, 0.f};
#pragma unroll
    for (int i = 0; i < QUADS; i++) *(float4*)&dst[(t + i * 256) * 4] = z;
    return;
  }
  int cnt = (1 + (cy > 0) + (cy < GWD - 1)) * (1 + (cx > 0) + (cx < GWD - 1)) - 1;
  float invc = 1.f / (float)cnt;
  float inv2M = (GWD == 6) ? 0.1f : (1.f / 15.f);
  float p0 = (cellpos(cx, GWD) - cellpos(sx, GWD)) * inv2M + 0.5f;
  float p1 = (cellpos(cy, GWD) - cellpos(sy, GWD)) * inv2M + 0.5f;
  int k00, k01, k10, k11; float w00, w01, w10, w11;
  corners(p0, p1, k00, k01, k10, k11, w00, w01, w10, w11);
  const float* W0 = W + (size_t)k00 * F * 64;
  const float* W1p = W + (size_t)k01 * F * 64;
  const float* W2p = W + (size_t)k10 * F * 64;
  const float* W3p = W + (size_t)k11 * F * 64;
#pragma unroll
  for (int i = 0; i < QUADS; i++) {
    int q = (t + i * 256) * 4;
    float4 a0 = *(const float4*)&W0[q];
    float4 a1 = *(const float4*)&W1p[q];
    float4 a2 = *(const float4*)&W2p[q];
    float4 a3 = *(const float4*)&W3p[q];
    float4 v;
    v.x = invc * (w00 * a0.x + w01 * a1.x + w10 * a2.x + w11 * a3.x);
    v.y = invc * (w00 * a0.y + w01 * a1.y + w10 * a2.y + w11 * a3.y);
    v.z = invc * (w00 * a0.z + w01 * a1.z + w10 * a2.z + w11 * a3.z);
    v.w = invc * (w00 * a0.w + w01 * a1.w + w10 * a2.w + w11 * a3.w);
    *(float4*)&dst[q] = v;
  }
}

// ---------------- D1: s1p1 || prepM2 || prepM3 -----------------------------
__global__ __launch_bounds__(256) void prep_kernel(
    const float* __restrict__ x, const float* __restrict__ W1,
    const float* __restrict__ root1, const float* __restrict__ b1,
    const float* __restrict__ W2, const float* __restrict__ root2,
    const float* __restrict__ W3, const float* __restrict__ root3,
    float* __restrict__ h1p, float* __restrict__ M2, float* __restrict__ M3) {
  int vb = blockIdx.x, t = threadIdx.x;
  if (vb < 1152)      s1p1_body(vb * 256 + t, x, W1, root1, b1, h1p);
  else if (vb < 1476) prepM_blk<32, 6>(vb - 1152, t, W2, root2, M2);
  else                prepM_blk<64, 4>(vb - 1476, t, W3, root3, M3);
}

// ------------------ class-GEMM: P[s][c][256][64] partials ------------------
// vb = (s*NC + c)*4 + rowtile; 256 threads, 64x64 tile, 4x4 acc. (R8 form)
template <int PER, int FSHIFT, int NC, int DPS, int GW>
DEV void gemm_body(int vb, int t, const float* __restrict__ X,
                   const float* __restrict__ M, float* __restrict__ P) {
  __shared__ float At[16][64];
  __shared__ float Bt[16][64];
  __shared__ int nbL[9];
  int s = vb / (4 * NC);
  int rem = vb - s * 4 * NC;
  int c = rem >> 2;
  int b0 = (rem & 3) * 64;
  constexpr int F = 1 << FSHIFT, fmask = F - 1;
  if (t < 9) {
    int cy = c / GW, cx = c % GW;
    int nbv = c;
    if (t < 8) {
      int sy = cy - c_dys[t], sx = cx - c_dxs[t];
      nbv = (sy >= 0 && sy < GW && sx >= 0 && sx < GW) ? sy * GW + sx : c;  // M==0
    }
    nbL[t] = nbv;
  }
  __syncthreads();

  int tx = t & 15, ty = t >> 4;
  int kqA = (t & 3) * 4, rA = t >> 2;     // A staging: 4 ks at kqA, row rA
  int bkB = t >> 4, bnB = (t & 15) * 4;   // B staging
  float acc[4][4];
#pragma unroll
  for (int i = 0; i < 4; i++)
#pragma unroll
    for (int j = 0; j < 4; j++) acc[i][j] = 0.f;

  constexpr int chunkK = DPS << FSHIFT;
  for (int k0 = 0; k0 < chunkK; k0 += 16) {
    int kA = k0 + kqA;
    int dA = s * DPS + (kA >> FSHIFT);
    int fA = kA & fmask;
    float4 xv = *(const float4*)&X[(((b0 + rA) * PER + nbL[dA]) << FSHIFT) + fA];
    int kB = k0 + bkB;
    int dB = s * DPS + (kB >> FSHIFT);
    int fB = kB & fmask;
    float4 bv = *(const float4*)&M[(size_t)(((c * 9 + dB) << FSHIFT) + fB) * 64 + bnB];
    __syncthreads();
    At[kqA + 0][rA] = xv.x; At[kqA + 1][rA] = xv.y;
    At[kqA + 2][rA] = xv.z; At[kqA + 3][rA] = xv.w;
    *(float4*)&Bt[bkB][bnB] = bv;
    __syncthreads();
#pragma unroll
    for (int kk = 0; kk < 16; kk++) {
      float4 a = *(const float4*)&At[kk][ty * 4];
      float4 bb = *(const float4*)&Bt[kk][tx * 4];
      acc[0][0] += a.x * bb.x; acc[0][1] += a.x * bb.y; acc[0][2] += a.x * bb.z; acc[0][3] += a.x * bb.w;
      acc[1][0] += a.y * bb.x; acc[1][1] += a.y * bb.y; acc[1][2] += a.y * bb.z; acc[1][3] += a.y * bb.w;
      acc[2][0] += a.z * bb.x; acc[2][1] += a.z * bb.y; acc[2][2] += a.z * bb.z; acc[2][3] += a.z * bb.w;
      acc[3][0] += a.w * bb.x; acc[3][1] += a.w * bb.y; acc[3][2] += a.w * bb.z; acc[3][3] += a.w * bb.w;
    }
  }
  float* Pq = P + ((size_t)(s * NC + c) * 256 + b0) * 64;
#pragma unroll
  for (int i = 0; i < 4; i++) {
    float4 v = {acc[i][0], acc[i][1], acc[i][2], acc[i][3]};
    *(float4*)&Pq[(size_t)(ty * 4 + i) * 64 + tx * 4] = v;
  }
}

template <int PER, int FSHIFT, int NC, int DPS, int GW>
__global__ __launch_bounds__(256) void gemm_cls_tk(
    const float* __restrict__ X, const float* __restrict__ M,
    float* __restrict__ P) {
  int vb = (blockIdx.z * NC + blockIdx.y) * 4 + blockIdx.x;
  gemm_body<PER, FSHIFT, NC, DPS, GW>(vb, threadIdx.x, X, M, P);
}

// ---- D3: sum 3 partials + bias + ELU + pool 6x6->4x4 -> h2p[b*16+cell] ----
__global__ __launch_bounds__(256) void redpool2_kernel(
    const float* __restrict__ P, const float* __restrict__ bias,
    float* __restrict__ h2p) {
  int id = blockIdx.x * 256 + threadIdx.x;  // 256*16*64 = 262144
  int g = id & 63, s2 = id >> 6;
  int b = s2 >> 4, r = s2 & 15;
  int oy = r >> 2, ox = r & 3;
  int ys = oy == 0 ? 0 : (oy == 1 ? 1 : (oy == 2 ? 3 : 4));
  int yn = (oy == 1 || oy == 3) ? 2 : 1;
  int xs = ox == 0 ? 0 : (ox == 1 ? 1 : (ox == 2 ? 3 : 4));
  int xn = (ox == 1 || ox == 3) ? 2 : 1;
  float bg = bias[g];
  const size_t CS = (size_t)36 * 256 * 64;
  float vmax = -3.4e38f;
  for (int yy = ys; yy < ys + yn; yy++)
    for (int xx = xs; xx < xs + xn; xx++) {
      size_t e = (size_t)((yy * 6 + xx) * 256 + b) * 64 + g;
      float v = P[e] + P[CS + e] + P[2 * CS + e] + bg;
      vmax = fmaxf(vmax, elu_f(v));
    }
  h2p[(size_t)s2 * 64 + g] = vmax;
}

// ---- D5: redpool3 (9 partials) + pool 4x4->2x2 + FC head, 1 block/image ---
__global__ __launch_bounds__(256) void fc_fused_kernel(
    const float* __restrict__ P, const float* __restrict__ b3,
    const float* __restrict__ fc1w, const float* __restrict__ fc1b,
    const float* __restrict__ fc2w, const float* __restrict__ fc2b,
    float* __restrict__ out) {
  __shared__ float h3[16][64];
  __shared__ float Al[256];
  __shared__ float part[256];
  __shared__ float h4[128];
  __shared__ float lg[10];
  int b = blockIdx.x, t = threadIdx.x;
  const size_t CS = (size_t)16 * 256 * 64;
#pragma unroll
  for (int i = 0; i < 4; i++) {
    int idx = i * 256 + t;            // 0..1023
    int cell = idx >> 6, g = idx & 63;
    float v = b3[g];
    size_t e = (size_t)(cell * 256 + b) * 64 + g;
#pragma unroll
    for (int q = 0; q < 9; q++) v += P[q * CS + e];
    h3[cell][g] = elu_f(v);
  }
  __syncthreads();
  {
    int r = t >> 6, g = t & 63;
    int oy = r >> 1, ox = r & 1;
    float m = -3.4e38f;
#pragma unroll
    for (int i = 0; i < 2; i++)
#pragma unroll
      for (int j = 0; j < 2; j++)
        m = fmaxf(m, h3[(oy * 2 + i) * 4 + (ox * 2 + j)][g]);
    Al[t] = m;
  }
  __syncthreads();
  {
    int o = t & 127, half = t >> 7;
    float acc = 0.f;
    const float* wcol = fc1w + o;
#pragma unroll 8
    for (int k = half * 128; k < half * 128 + 128; k++)
      acc += Al[k] * wcol[k * 128];
    part[t] = acc;
  }
  __syncthreads();
  if (t < 128)
    h4[t] = elu_f(part[t] + part[t + 128] + fc1b[t]);
  __syncthreads();
  if (t < 10) {
    float l = fc2b[t];
#pragma unroll 8
    for (int k = 0; k < 128; k++) l += h4[k] * fc2w[k * 10 + t];
    lg[t] = l;
  }
  __syncthreads();
  if (t < 10) {
    float m = lg[0];
#pragma unroll
    for (int j = 1; j < 10; j++) m = fmaxf(m, lg[j]);
    float ssum = 0.f;
#pragma unroll
    for (int j = 0; j < 10; j++) ssum += expf(lg[j] - m);
    out[b * 10 + t] = lg[t] - m - logf(ssum);
  }
}

// ---------------------------------------------------------------------------
extern "C" void kernel_launch(void* const* d_in, const int* in_sizes, int n_in,
                              void* d_out, int out_size, void* d_ws, size_t ws_size,
                              hipStream_t stream) {
  const float* x     = (const float*)d_in[0];
  const float* W1    = (const float*)d_in[3];
  const float* root1 = (const float*)d_in[4];
  const float* b1    = (const float*)d_in[5];
  const float* W2    = (const float*)d_in[6];
  const float* root2 = (const float*)d_in[7];
  const float* b2    = (const float*)d_in[8];
  const float* W3    = (const float*)d_in[9];
  const float* root3 = (const float*)d_in[10];
  const float* b3    = (const float*)d_in[11];
  const float* fc1w  = (const float*)d_in[12];
  const float* fc1b  = (const float*)d_in[13];
  const float* fc2w  = (const float*)d_in[14];
  const float* fc2b  = (const float*)d_in[15];
  float* out = (float*)d_out;

  float* ws = (float*)d_ws;
  size_t o = 0;
  float* w_h1p = ws + o; o += (size_t)9216 * 32;          // 294912
  float* w_M2  = ws + o; o += (size_t)36 * 9 * 32 * 64;   // 663552
  float* w_M3  = ws + o; o += (size_t)16 * 9 * 64 * 64;   // 589824
  float* w_P   = ws + o; o += (size_t)9 * 16 * 256 * 64;  // 2359296 (>= L2's 3*36*256*64)
  float* w_h2p = ws + o; o += (size_t)4096 * 64;

  // D1: s1p1 (1152) || prepM2 (324) || prepM3 (144)
  prep_kernel<<<1620, 256, 0, stream>>>(x, W1, root1, b1, W2, root2, W3, root3,
                                        w_h1p, w_M2, w_M3);
  // D2: L2 class-GEMM, 36c x 4 rowtiles x S=3 = 432 blocks
  gemm_cls_tk<36, 5, 36, 3, 6><<<dim3(4, 36, 3), 256, 0, stream>>>(w_h1p, w_M2, w_P);
  // D3: reduce+ELU+pool 6x6->4x4
  redpool2_kernel<<<1024, 256, 0, stream>>>(w_P, b2, w_h2p);
  // D4: L3 class-GEMM, 16c x 4 rowtiles x S=9 = 576 blocks
  gemm_cls_tk<16, 6, 16, 1, 4><<<dim3(4, 16, 9), 256, 0, stream>>>(w_h2p, w_M3, w_P);
  // D5: redpool3 + FC head fused
  fc_fused_kernel<<<256, 256, 0, stream>>>(w_P, b3, fc1w, fc1b, fc2w, fc2b, out);
}